// Round 5
// baseline (1607.127 us; speedup 1.0000x reference)
//
#include <hip/hip_runtime.h>
#include <cstdint>
#include <cmath>

#define N0   6144
#define FD   320
#define NN1  4915
#define NN2  2949
#define CAP  384

// ---------------- adjacency build: dense row -> compact column list ----------------
__global__ __launch_bounds__(256) void build_adj_k(const float* __restrict__ A,
                                                   int* __restrict__ adj, int* __restrict__ deg) {
  int w = blockIdx.x * 4 + (threadIdx.x >> 6);
  int lane = threadIdx.x & 63;
  if (w >= N0) return;
  const float* row = A + (size_t)w * N0;
  int* dst = adj + (size_t)w * CAP;
  int base = 0;
  unsigned long long lm = (1ull << lane) - 1ull;
  for (int j0 = 0; j0 < N0; j0 += 256) {
    float4 v = *(const float4*)(row + j0 + (lane << 2));
    bool f0 = v.x > 0.f, f1 = v.y > 0.f, f2 = v.z > 0.f, f3 = v.w > 0.f;
    unsigned long long m0 = __ballot(f0), m1 = __ballot(f1), m2 = __ballot(f2), m3 = __ballot(f3);
    int p = base + __popcll(m0 & lm) + __popcll(m1 & lm) + __popcll(m2 & lm) + __popcll(m3 & lm);
    int c0 = j0 + (lane << 2);
    if (f0) dst[p++] = c0;
    if (f1) dst[p++] = c0 + 1;
    if (f2) dst[p++] = c0 + 2;
    if (f3) dst[p++] = c0 + 3;
    base += __popcll(m0) + __popcll(m1) + __popcll(m2) + __popcll(m3);
  }
  if (lane == 0) deg[w] = base;
}

// subgraph adjacency: new row r <- old row idx[r], keep cols with inv[c]>=0, renumber
__global__ __launch_bounds__(256) void sub_adj_k(const int* __restrict__ adjs, const int* __restrict__ degs,
                                                 const int* __restrict__ idx, const int* __restrict__ inv,
                                                 int* __restrict__ adjd, int* __restrict__ degd, int k) {
  int w = blockIdx.x * 4 + (threadIdx.x >> 6);
  int lane = threadIdx.x & 63;
  if (w >= k) return;
  int o = idx[w];
  int d = degs[o];
  const int* src = adjs + (size_t)o * CAP;
  int* dst = adjd + (size_t)w * CAP;
  int base = 0;
  for (int t0 = 0; t0 < d; t0 += 64) {
    int tt = t0 + lane;
    int p = -1;
    if (tt < d) p = inv[src[tt]];
    unsigned long long m = __ballot(p >= 0);
    if (p >= 0) dst[base + __popcll(m & ((1ull << lane) - 1ull))] = p;
    base += (int)__popcll(m);
  }
  if (lane == 0) degd[w] = base;
}

// ================= tiled gather family, column-split for L2 locality =================
// One wave per row; (index, weight) staged once in LDS, then TWO passes over
// 160-column halves (working set per phase fits the 4 MiB per-XCD L2).
// Per half: 8 neighbors in flight (group g = lane>>3), sub = lane&7 covers
// cols sub*4 + 32*c (c=0..4) as float4; xor-reduce over groups {8,16,32};
// groups 0..4 store chunk c = g.

#define GATHER_HALF(XSRC, HB)                                                    \
  a0 = make_float4(0,0,0,0); a1 = a0; a2 = a0; a3 = a0; a4 = a0;                 \
  _Pragma("unroll 2")                                                            \
  for (int t = 0; t < d; t += 8) {                                               \
    int jj = lj[t + g];                                                          \
    float ww = lw[t + g];                                                        \
    const float* bp = XSRC + (size_t)jj * FD + (HB) + (sub << 2);                \
    float4 v0 = *(const float4*)(bp);                                            \
    float4 v1 = *(const float4*)(bp + 32);                                       \
    float4 v2 = *(const float4*)(bp + 64);                                       \
    float4 v3 = *(const float4*)(bp + 96);                                       \
    float4 v4 = *(const float4*)(bp + 128);                                      \
    a0.x = fmaf(ww, v0.x, a0.x); a0.y = fmaf(ww, v0.y, a0.y);                    \
    a0.z = fmaf(ww, v0.z, a0.z); a0.w = fmaf(ww, v0.w, a0.w);                    \
    a1.x = fmaf(ww, v1.x, a1.x); a1.y = fmaf(ww, v1.y, a1.y);                    \
    a1.z = fmaf(ww, v1.z, a1.z); a1.w = fmaf(ww, v1.w, a1.w);                    \
    a2.x = fmaf(ww, v2.x, a2.x); a2.y = fmaf(ww, v2.y, a2.y);                    \
    a2.z = fmaf(ww, v2.z, a2.z); a2.w = fmaf(ww, v2.w, a2.w);                    \
    a3.x = fmaf(ww, v3.x, a3.x); a3.y = fmaf(ww, v3.y, a3.y);                    \
    a3.z = fmaf(ww, v3.z, a3.z); a3.w = fmaf(ww, v3.w, a3.w);                    \
    a4.x = fmaf(ww, v4.x, a4.x); a4.y = fmaf(ww, v4.y, a4.y);                    \
    a4.z = fmaf(ww, v4.z, a4.z); a4.w = fmaf(ww, v4.w, a4.w);                    \
  }                                                                              \
  _Pragma("unroll")                                                              \
  for (int off = 8; off <= 32; off <<= 1) {                                      \
    a0.x += __shfl_xor(a0.x, off); a0.y += __shfl_xor(a0.y, off);                \
    a0.z += __shfl_xor(a0.z, off); a0.w += __shfl_xor(a0.w, off);                \
    a1.x += __shfl_xor(a1.x, off); a1.y += __shfl_xor(a1.y, off);                \
    a1.z += __shfl_xor(a1.z, off); a1.w += __shfl_xor(a1.w, off);                \
    a2.x += __shfl_xor(a2.x, off); a2.y += __shfl_xor(a2.y, off);                \
    a2.z += __shfl_xor(a2.z, off); a2.w += __shfl_xor(a2.w, off);                \
    a3.x += __shfl_xor(a3.x, off); a3.y += __shfl_xor(a3.y, off);                \
    a3.z += __shfl_xor(a3.z, off); a3.w += __shfl_xor(a3.w, off);                \
    a4.x += __shfl_xor(a4.x, off); a4.y += __shfl_xor(a4.y, off);                \
    a4.z += __shfl_xor(a4.z, off); a4.w += __shfl_xor(a4.w, off);                \
  }                                                                              \
  osel = (g == 0) ? a0 : (g == 1) ? a1 : (g == 2) ? a2 : (g == 3) ? a3 : a4;

#define GATHER_DECL                                                              \
  int sub = lane & 7, g = lane >> 3;                                             \
  float4 a0, a1, a2, a3, a4, osel;

// Y[r,:] = sum_{j in N(r)} X[j,:]
__global__ __launch_bounds__(256) void spmm_k(const int* __restrict__ adj, const int* __restrict__ deg,
                                              const float* __restrict__ X, float* __restrict__ Y, int n) {
  __shared__ int ljs[4][CAP];
  __shared__ float lws[4][CAP];
  int wv = threadIdx.x >> 6, lane = threadIdx.x & 63;
  int w = blockIdx.x * 4 + wv;
  if (w >= n) return;
  int* lj = ljs[wv]; float* lw = lws[wv];
  int d = deg[w];
  const int* row = adj + (size_t)w * CAP;
  for (int t0 = 0; t0 < d; t0 += 64) {
    int tt = t0 + lane;
    lj[tt] = (tt < d) ? row[tt] : 0;
    lw[tt] = (tt < d) ? 1.0f : 0.0f;
  }
  GATHER_DECL
  float* yr = Y + (size_t)w * FD;
#pragma unroll
  for (int hb = 0; hb < FD; hb += 160) {
    GATHER_HALF(X, hb)
    if (g < 5) *(float4*)(yr + hb + (g << 5) + (sub << 2)) = osel;
  }
}

// gather-scaled spmm: Y[r,:] = sum_{j in N(r)} vals[j] * Xsrc[idxmap[j], :]
__global__ __launch_bounds__(256) void spmm_gs_k(const int* __restrict__ adj, const int* __restrict__ deg,
                                                 const int* __restrict__ idxmap, const float* __restrict__ vals,
                                                 const float* __restrict__ Xsrc, float* __restrict__ Y, int n) {
  __shared__ int ljs[4][CAP];
  __shared__ float lws[4][CAP];
  int wv = threadIdx.x >> 6, lane = threadIdx.x & 63;
  int w = blockIdx.x * 4 + wv;
  if (w >= n) return;
  int* lj = ljs[wv]; float* lw = lws[wv];
  int d = deg[w];
  const int* row = adj + (size_t)w * CAP;
  for (int t0 = 0; t0 < d; t0 += 64) {
    int tt = t0 + lane;
    int j = (tt < d) ? row[tt] : -1;
    lj[tt] = (j >= 0) ? idxmap[j] : 0;
    lw[tt] = (j >= 0) ? vals[j] : 0.0f;
  }
  GATHER_DECL
  float* yr = Y + (size_t)w * FD;
#pragma unroll
  for (int hb = 0; hb < FD; hb += 160) {
    GATHER_HALF(Xsrc, hb)
    if (g < 5) *(float4*)(yr + hb + (g << 5) + (sub << 2)) = osel;
  }
}

// fused unpool + A@Xn: source row = inv[col] into pooled X, skip if -1
__global__ __launch_bounds__(256) void mspmm_k(const int* __restrict__ adj, const int* __restrict__ deg,
                                               const int* __restrict__ inv,
                                               const float* __restrict__ Xp, float* __restrict__ Y, int n) {
  __shared__ int ljs[4][CAP];
  __shared__ float lws[4][CAP];
  int wv = threadIdx.x >> 6, lane = threadIdx.x & 63;
  int w = blockIdx.x * 4 + wv;
  if (w >= n) return;
  int* lj = ljs[wv]; float* lw = lws[wv];
  int d = deg[w];
  const int* row = adj + (size_t)w * CAP;
  for (int t0 = 0; t0 < d; t0 += 64) {
    int tt = t0 + lane;
    int p = -1;
    if (tt < d) p = inv[row[tt]];
    lj[tt] = p >= 0 ? p : 0;
    lw[tt] = p >= 0 ? 1.0f : 0.0f;
  }
  GATHER_DECL
  float* yr = Y + (size_t)w * FD;
#pragma unroll
  for (int hb = 0; hb < FD; hb += 160) {
    GATHER_HALF(Xp, hb)
    if (g < 5) *(float4*)(yr + hb + (g << 5) + (sub << 2)) = osel;
  }
}

// fused masked-softmax GAT row: out = elu( softmax_edges(LR(es_i+ed_j)) @ h )
__global__ __launch_bounds__(256) void gat_k(const int* __restrict__ adj, const int* __restrict__ deg,
                                             const float* __restrict__ h, const float* __restrict__ es,
                                             const float* __restrict__ ed, float* __restrict__ out, int n) {
  __shared__ int ljs[4][CAP];
  __shared__ float lws[4][CAP];
  int wv = threadIdx.x >> 6, lane = threadIdx.x & 63;
  int w = blockIdx.x * 4 + wv;
  if (w >= n) return;
  int* lj = ljs[wv]; float* lw = lws[wv];
  int d = deg[w];
  const int* row = adj + (size_t)w * CAP;
  float esr = es[w];
  float m = -INFINITY;
  for (int t0 = 0; t0 < d; t0 += 64) {
    int tt = t0 + lane;
    int j = (tt < d) ? row[tt] : 0;
    float e = -INFINITY;
    if (tt < d) {
      e = esr + ed[j];
      e = e >= 0.f ? e : 0.2f * e;
    }
    lj[tt] = j;
    lw[tt] = e;
    m = fmaxf(m, e);
  }
  #pragma unroll
  for (int off = 32; off; off >>= 1) m = fmaxf(m, __shfl_xor(m, off));
  float zacc = 0.f;
  for (int t0 = 0; t0 < d; t0 += 64) {
    int tt = t0 + lane;
    float wgt = expf(lw[tt] - m);
    lw[tt] = wgt;
    zacc += wgt;
  }
  #pragma unroll
  for (int off = 32; off; off >>= 1) zacc += __shfl_xor(zacc, off);
  GATHER_DECL
  float* yr = out + (size_t)w * FD;
#pragma unroll
  for (int hb = 0; hb < FD; hb += 160) {
    GATHER_HALF(h, hb)
    if (g < 5) {
      float4 o;
      o.x = osel.x / zacc; o.y = osel.y / zacc; o.z = osel.z / zacc; o.w = osel.w / zacc;
      o.x = o.x > 0.f ? o.x : expm1f(o.x);
      o.y = o.y > 0.f ? o.y : expm1f(o.y);
      o.z = o.z > 0.f ? o.z : expm1f(o.z);
      o.w = o.w > 0.f ? o.w : expm1f(o.w);
      *(float4*)(yr + hb + (g << 5) + (sub << 2)) = o;
    }
  }
}

// ---------------- fp32 tiled GEMM: C[n x 320] = A[n x K] @ W[K x 320] (+bias)(+add) ----------------
// Optional: A2 column-concat (k >= ksplit reads A2); rowidx/rowscale row-gather
// (A row = rowidx[r], scaled by rowscale[r] — fuses pool-gather into the GEMM).
__global__ __launch_bounds__(256) void gemm_k(const float* __restrict__ A, const float* __restrict__ A2,
                                              int ksplit,
                                              const int* __restrict__ rowidx, const float* __restrict__ rowscale,
                                              const float* __restrict__ W,
                                              const float* __restrict__ bias, const float* __restrict__ add,
                                              float* __restrict__ C, int n, int K) {
  __shared__ float As[16][68];
  __shared__ float Bs[16][68];
  int t = threadIdx.x;
  int tx = t & 15, ty = t >> 4;
  int row0 = blockIdx.x * 64, col0 = blockIdx.y * 64;
  float acc[4][4] = {};
  int ar = t >> 2;
  int ak = (t & 3) << 2;
  int bk = t >> 4;
  int bc = (t & 15) << 2;
  int grow = row0 + ar;
  int srow = grow;
  float sscale = 1.0f;
  if (grow < n && rowidx) { srow = rowidx[grow]; sscale = rowscale[grow]; }
  for (int k0 = 0; k0 < K; k0 += 16) {
    float4 av = make_float4(0.f, 0.f, 0.f, 0.f);
    int kk = k0 + ak;
    if (grow < n) {
      const float* src;
      if (A2 && kk >= ksplit) src = A2 + (size_t)srow * (K - ksplit) + (kk - ksplit);
      else                    src = A  + (size_t)srow * (A2 ? ksplit : K) + kk;
      av = *(const float4*)src;
      if (rowidx) { av.x *= sscale; av.y *= sscale; av.z *= sscale; av.w *= sscale; }
    }
    As[ak + 0][ar] = av.x; As[ak + 1][ar] = av.y; As[ak + 2][ar] = av.z; As[ak + 3][ar] = av.w;
    float4 bv = *(const float4*)(W + (size_t)(k0 + bk) * FD + col0 + bc);
    *(float4*)&Bs[bk][bc] = bv;
    __syncthreads();
#pragma unroll
    for (int kkk = 0; kkk < 16; ++kkk) {
      float af[4], bf[4];
      *(float4*)af = *(const float4*)&As[kkk][ty << 2];
      *(float4*)bf = *(const float4*)&Bs[kkk][tx << 2];
#pragma unroll
      for (int i = 0; i < 4; ++i)
#pragma unroll
        for (int j = 0; j < 4; ++j) acc[i][j] = fmaf(af[i], bf[j], acc[i][j]);
    }
    __syncthreads();
  }
#pragma unroll
  for (int i = 0; i < 4; ++i) {
    int r = row0 + (ty << 2) + i;
    if (r >= n) continue;
    int c = col0 + (tx << 2);
    float4 v;
    v.x = acc[i][0]; v.y = acc[i][1]; v.z = acc[i][2]; v.w = acc[i][3];
    if (bias) { v.x += bias[c]; v.y += bias[c + 1]; v.z += bias[c + 2]; v.w += bias[c + 3]; }
    if (add) {
      const float* ad = add + (size_t)r * FD + c;
      v.x += ad[0]; v.y += ad[1]; v.z += ad[2]; v.w += ad[3];
    }
    *(float4*)(C + (size_t)r * FD + c) = v;
  }
}

static inline unsigned cdiv(int a, int b) { return (unsigned)((a + b - 1) / b); }

static void launch_gemm(const float* A, const float* W, const float* bias, const float* add,
                        float* C, int n, int K, hipStream_t stream, const float* A2 = nullptr,
                        int ksplit = 0, const int* rowidx = nullptr, const float* rowscale = nullptr) {
  gemm_k<<<dim3(cdiv(n, 64), 5), dim3(256), 0, stream>>>(A, A2, ksplit, rowidx, rowscale,
                                                         W, bias, add, C, n, K);
}

// ---------------- GAT helpers ----------------
__global__ __launch_bounds__(256) void esed_k(const float* __restrict__ h, const float* __restrict__ a,
                                              float* __restrict__ es, float* __restrict__ ed, int n) {
  int w = blockIdx.x * 4 + (threadIdx.x >> 6);
  int lane = threadIdx.x & 63;
  if (w >= n) return;
  const float* hr = h + (size_t)w * FD;
  const float* a2 = a + FD;
  float sa = 0.f, sb = 0.f;
#pragma unroll
  for (int c = 0; c < 5; ++c) {
    float hv = hr[lane + 64 * c];
    sa += hv * a[lane + 64 * c];
    sb += hv * a2[lane + 64 * c];
  }
  for (int o = 32; o; o >>= 1) { sa += __shfl_xor(sa, o); sb += __shfl_xor(sb, o); }
  if (lane == 0) { es[w] = sa; ed[w] = sb; }
}

// ---------------- pooling: fused score + key build + rank zero ----------------
__global__ __launch_bounds__(256) void scorekey_k(const float* __restrict__ X, const float* __restrict__ pw,
                                                  const float* __restrict__ pb,
                                                  unsigned long long* __restrict__ keys,
                                                  int* __restrict__ rank, int n) {
  int w = blockIdx.x * 4 + (threadIdx.x >> 6);
  int lane = threadIdx.x & 63;
  if (w >= n) return;
  const float* xr = X + (size_t)w * FD;
  float s = 0.f;
#pragma unroll
  for (int c = 0; c < 5; ++c) s += xr[lane + 64 * c] * pw[lane + 64 * c];
  for (int o = 32; o; o >>= 1) s += __shfl_xor(s, o);
  if (lane == 0) {
    float u = (s + pb[0]) / 100.0f;
    float sc = 1.0f / (1.0f + expf(-u));
    keys[w] = ((unsigned long long)__float_as_uint(sc) << 32) | (unsigned int)(~w);
    rank[w] = 0;
  }
}

#define RANK_TILE 1024
__global__ __launch_bounds__(256) void rank_count_k(const unsigned long long* __restrict__ keys,
                                                    int n, int jchunk, int* __restrict__ rank) {
  __shared__ unsigned long long tile[RANK_TILE];
  int i = blockIdx.x * 256 + threadIdx.x;
  unsigned long long my = (i < n) ? keys[i] : 0ull;
  int j0 = blockIdx.y * jchunk;
  int jend = j0 + jchunk; if (jend > n) jend = n;
  int cnt = 0;
  for (int t0 = j0; t0 < jend; t0 += RANK_TILE) {
    int m = jend - t0; if (m > RANK_TILE) m = RANK_TILE;
    for (int t = threadIdx.x; t < m; t += 256) tile[t] = keys[t0 + t];
    __syncthreads();
    for (int t = 0; t < m; ++t) cnt += (tile[t] > my) ? 1 : 0;
    __syncthreads();
  }
  if (i < n && cnt) atomicAdd(&rank[i], cnt);
}

__global__ __launch_bounds__(256) void rank_scatter_k(const unsigned long long* __restrict__ keys,
                                                      const int* __restrict__ rank, int n, int k,
                                                      int* __restrict__ idx_out, float* __restrict__ vals_out,
                                                      int* __restrict__ inv) {
  int i = blockIdx.x * 256 + threadIdx.x;
  if (i >= n) return;
  int r = rank[i];
  inv[i] = (r < k) ? r : -1;
  if (r < k) {
    idx_out[r] = i;
    vals_out[r] = __uint_as_float((unsigned int)(keys[i] >> 32));
  }
}

// ---------------- host ----------------
static inline dim3 wgrid(int n) { return dim3((unsigned)((n + 3) / 4)); }

struct TopkBufs { unsigned long long* keys; int* rank; };

static void launch_topk(int n, int k, int* idx_out, float* vals_out, int* inv,
                        TopkBufs tb, hipStream_t stream) {
  const int JS = 8;
  int jchunk = (n + JS - 1) / JS;
  rank_count_k<<<dim3(cdiv(n, 256), JS), dim3(256), 0, stream>>>(tb.keys, n, jchunk, tb.rank);
  rank_scatter_k<<<cdiv(n, 256), dim3(256), 0, stream>>>(tb.keys, tb.rank, n, k, idx_out, vals_out, inv);
}

extern "C" void kernel_launch(void* const* d_in, const int* in_sizes, int n_in,
                              void* d_out, int out_size, void* d_ws, size_t ws_size,
                              hipStream_t stream) {
  const float* A      = (const float*)d_in[0];
  const float* X0     = (const float*)d_in[1];
  const float* sg_W   = (const float*)d_in[2];
  const float* sg_a   = (const float*)d_in[3];
  const float* bg_W   = (const float*)d_in[4];
  const float* bg_a   = (const float*)d_in[5];
  const float* eg_W   = (const float*)d_in[6];
  const float* eg_a   = (const float*)d_in[7];
  const float* down_W = (const float*)d_in[8];
  const float* down_b = (const float*)d_in[9];
  const float* up_W   = (const float*)d_in[10];
  const float* up_b   = (const float*)d_in[11];
  const float* pool_w = (const float*)d_in[12];
  const float* pool_b = (const float*)d_in[13];
  float* out = (float*)d_out;
  char* ws = (char*)d_ws;

  size_t off = 0;
  auto alloc = [&](size_t bytes) -> char* {
    char* p = ws + off;
    off += (bytes + 255) & ~(size_t)255;
    return p;
  };
  int* adj0  = (int*)alloc((size_t)N0 * CAP * 4);
  int* deg0  = (int*)alloc((size_t)N0 * 4);
  int* adj1a = (int*)alloc((size_t)NN1 * CAP * 4);
  int* deg1a = (int*)alloc((size_t)NN1 * 4);
  int* adj1b = (int*)alloc((size_t)NN1 * CAP * 4);
  int* deg1b = (int*)alloc((size_t)NN1 * 4);
  int* adj2  = (int*)alloc((size_t)NN2 * CAP * 4);
  int* deg2  = (int*)alloc((size_t)NN2 * 4);
  int* inv0a = (int*)alloc((size_t)N0 * 4);
  int* inv0b = (int*)alloc((size_t)N0 * 4);
  int* inv1a = (int*)alloc((size_t)NN1 * 4);
  int* inv1b = (int*)alloc((size_t)NN1 * 4);
  int* idx0a = (int*)alloc((size_t)NN1 * 4);
  int* idx0b = (int*)alloc((size_t)NN1 * 4);
  int* idx1a = (int*)alloc((size_t)NN2 * 4);
  int* idx1b = (int*)alloc((size_t)NN2 * 4);
  unsigned long long* keys = (unsigned long long*)alloc((size_t)N0 * 8);
  int* rankb = (int*)alloc((size_t)N0 * 4);
  float* vals   = (float*)alloc((size_t)N0 * 4);
  float* es     = (float*)alloc((size_t)N0 * 4);
  float* ed     = (float*)alloc((size_t)N0 * 4);
  float* hbuf   = (float*)alloc((size_t)N0 * FD * 4);
  float* S      = (float*)alloc((size_t)N0 * FD * 4);
  float* Xcur   = (float*)alloc((size_t)N0 * FD * 4);
  float* d0a    = (float*)alloc((size_t)N0 * FD * 4);
  float* d1a    = (float*)alloc((size_t)NN1 * FD * 4);
  float* d0b    = (float*)alloc((size_t)N0 * FD * 4);
  float* d1b    = (float*)alloc((size_t)NN1 * FD * 4);
  float* Xb     = (float*)alloc((size_t)NN2 * FD * 4);
  float* Xu1    = (float*)alloc((size_t)NN1 * FD * 4);
  float* Xu0    = (float*)alloc((size_t)N0 * FD * 4);

  TopkBufs tb{keys, rankb};
  dim3 b256(256);

  build_adj_k<<<wgrid(N0), b256, 0, stream>>>(A, adj0, deg0);

  float* orgX = out + (size_t)N0 * FD;   // "start" output, also org_X
  launch_gemm(X0, sg_W, nullptr, nullptr, hbuf, N0, FD, stream);
  esed_k<<<wgrid(N0), b256, 0, stream>>>(hbuf, sg_a, es, ed, N0);
  gat_k<<<wgrid(N0), b256, 0, stream>>>(adj0, deg0, hbuf, es, ed, orgX, N0);

  const float* Xin = orgX;
  for (int pass = 0; pass < 2; ++pass) {
    int* idx0p = pass ? idx0b : idx0a;
    int* inv0p = pass ? inv0b : inv0a;
    int* idx1p = pass ? idx1b : idx1a;
    int* inv1p = pass ? inv1b : inv1a;
    int* adj1p = pass ? adj1b : adj1a;
    int* deg1p = pass ? deg1b : deg1a;
    float* d0p = pass ? d0b : d0a;
    float* d1p = pass ? d1b : d1a;

    // ---- down level 0 (n = N0) ----
    spmm_k<<<wgrid(N0), b256, 0, stream>>>(adj0, deg0, Xin, S, N0);
    launch_gemm(S, down_W, down_b, nullptr, d0p, N0, FD, stream);
    scorekey_k<<<wgrid(N0), b256, 0, stream>>>(d0p, pool_w, pool_b, keys, rankb, N0);
    launch_topk(N0, NN1, idx0p, vals, inv0p, tb, stream);
    sub_adj_k<<<wgrid(NN1), b256, 0, stream>>>(adj0, deg0, idx0p, inv0p, adj1p, deg1p, NN1);

    // ---- down level 1 (n = NN1): pool-gather fused into the spmm ----
    spmm_gs_k<<<wgrid(NN1), b256, 0, stream>>>(adj1p, deg1p, idx0p, vals, d0p, S, NN1);
    launch_gemm(S, down_W + FD * FD, down_b + FD, nullptr, d1p, NN1, FD, stream);
    scorekey_k<<<wgrid(NN1), b256, 0, stream>>>(d1p, pool_w + FD, pool_b + 1, keys, rankb, NN1);
    launch_topk(NN1, NN2, idx1p, vals, inv1p, tb, stream);
    sub_adj_k<<<wgrid(NN2), b256, 0, stream>>>(adj1p, deg1p, idx1p, inv1p, adj2, deg2, NN2);

    // ---- bottom GAT (n = NN2): pool-gather fused into the GEMM A-loader ----
    launch_gemm(d1p, bg_W, nullptr, nullptr, hbuf, NN2, FD, stream, nullptr, 0, idx1p, vals);
    esed_k<<<wgrid(NN2), b256, 0, stream>>>(hbuf, bg_a, es, ed, NN2);
    gat_k<<<wgrid(NN2), b256, 0, stream>>>(adj2, deg2, hbuf, es, ed, Xb, NN2);

    // ---- up path: ALWAYS pass-1 ("a") graph state, per reference indexing ----
    mspmm_k<<<wgrid(NN1), b256, 0, stream>>>(adj1a, deg1a, inv1a, Xb, S, NN1);
    launch_gemm(S, up_W, up_b, d1a, Xu1, NN1, FD, stream);
    mspmm_k<<<wgrid(N0), b256, 0, stream>>>(adj0, deg0, inv0a, Xu1, S, N0);
    launch_gemm(S, up_W + FD * FD, up_b + FD, d0a, Xu0, N0, FD, stream);

    // ---- end GAT on concat([Xu0, org_X]) fused into the GEMM A-loader ----
    launch_gemm(Xu0, eg_W, nullptr, nullptr, hbuf, N0, 2 * FD, stream, orgX, FD);
    esed_k<<<wgrid(N0), b256, 0, stream>>>(hbuf, eg_a, es, ed, N0);
    float* egout = pass ? out : Xcur;
    gat_k<<<wgrid(N0), b256, 0, stream>>>(adj0, deg0, hbuf, es, ed, egout, N0);
    Xin = egout;
  }
}

// Round 6
// 1469.646 us; speedup vs baseline: 1.0935x; 1.0935x over previous
//
#include <hip/hip_runtime.h>
#include <cstdint>
#include <cmath>

#define N0   6144
#define FD   320
#define NN1  4915
#define NN2  2949
#define CAP  384

// ---------------- adjacency build: dense row -> compact column list ----------------
__global__ __launch_bounds__(256) void build_adj_k(const float* __restrict__ A,
                                                   int* __restrict__ adj, int* __restrict__ deg) {
  int w = blockIdx.x * 4 + (threadIdx.x >> 6);
  int lane = threadIdx.x & 63;
  if (w >= N0) return;
  const float* row = A + (size_t)w * N0;
  int* dst = adj + (size_t)w * CAP;
  int base = 0;
  unsigned long long lm = (1ull << lane) - 1ull;
  for (int j0 = 0; j0 < N0; j0 += 256) {
    float4 v = *(const float4*)(row + j0 + (lane << 2));
    bool f0 = v.x > 0.f, f1 = v.y > 0.f, f2 = v.z > 0.f, f3 = v.w > 0.f;
    unsigned long long m0 = __ballot(f0), m1 = __ballot(f1), m2 = __ballot(f2), m3 = __ballot(f3);
    int p = base + __popcll(m0 & lm) + __popcll(m1 & lm) + __popcll(m2 & lm) + __popcll(m3 & lm);
    int c0 = j0 + (lane << 2);
    if (f0) dst[p++] = c0;
    if (f1) dst[p++] = c0 + 1;
    if (f2) dst[p++] = c0 + 2;
    if (f3) dst[p++] = c0 + 3;
    base += __popcll(m0) + __popcll(m1) + __popcll(m2) + __popcll(m3);
  }
  if (lane == 0) deg[w] = base;
}

// subgraph adjacency: new row r <- old row idx[r], keep cols with inv[c]>=0, renumber
__global__ __launch_bounds__(256) void sub_adj_k(const int* __restrict__ adjs, const int* __restrict__ degs,
                                                 const int* __restrict__ idx, const int* __restrict__ inv,
                                                 int* __restrict__ adjd, int* __restrict__ degd, int k) {
  int w = blockIdx.x * 4 + (threadIdx.x >> 6);
  int lane = threadIdx.x & 63;
  if (w >= k) return;
  int o = idx[w];
  int d = degs[o];
  const int* src = adjs + (size_t)o * CAP;
  int* dst = adjd + (size_t)w * CAP;
  int base = 0;
  for (int t0 = 0; t0 < d; t0 += 64) {
    int tt = t0 + lane;
    int p = -1;
    if (tt < d) p = inv[src[tt]];
    unsigned long long m = __ballot(p >= 0);
    if (p >= 0) dst[base + __popcll(m & ((1ull << lane) - 1ull))] = p;
    base += (int)__popcll(m);
  }
  if (lane == 0) degd[w] = base;
}

// ================= tiled gather family (R4 structure: one full-row visit per neighbor) ======
// One wave per row. (index, weight) staged in LDS; 4 neighbors in flight
// (group g = lane>>4), sub = lane&15 covers cols sub*4 + 64*c (c=0..4) as float4;
// xor-reduce over groups {16,32}; group g stores chunk g, group 0 also chunk 4.
#define GATHER_CORE(XSRC)                                                        \
  int sub = lane & 15, g = lane >> 4;                                            \
  float4 a0 = {0,0,0,0}, a1 = {0,0,0,0}, a2 = {0,0,0,0}, a3 = {0,0,0,0}, a4 = {0,0,0,0}; \
  _Pragma("unroll 2")                                                            \
  for (int t = 0; t < d; t += 4) {                                               \
    int jj = lj[t + g];                                                          \
    float ww = lw[t + g];                                                        \
    const float* base = XSRC + (size_t)jj * FD + (sub << 2);                     \
    float4 v0 = *(const float4*)(base);                                          \
    float4 v1 = *(const float4*)(base + 64);                                     \
    float4 v2 = *(const float4*)(base + 128);                                    \
    float4 v3 = *(const float4*)(base + 192);                                    \
    float4 v4 = *(const float4*)(base + 256);                                    \
    a0.x = fmaf(ww, v0.x, a0.x); a0.y = fmaf(ww, v0.y, a0.y);                    \
    a0.z = fmaf(ww, v0.z, a0.z); a0.w = fmaf(ww, v0.w, a0.w);                    \
    a1.x = fmaf(ww, v1.x, a1.x); a1.y = fmaf(ww, v1.y, a1.y);                    \
    a1.z = fmaf(ww, v1.z, a1.z); a1.w = fmaf(ww, v1.w, a1.w);                    \
    a2.x = fmaf(ww, v2.x, a2.x); a2.y = fmaf(ww, v2.y, a2.y);                    \
    a2.z = fmaf(ww, v2.z, a2.z); a2.w = fmaf(ww, v2.w, a2.w);                    \
    a3.x = fmaf(ww, v3.x, a3.x); a3.y = fmaf(ww, v3.y, a3.y);                    \
    a3.z = fmaf(ww, v3.z, a3.z); a3.w = fmaf(ww, v3.w, a3.w);                    \
    a4.x = fmaf(ww, v4.x, a4.x); a4.y = fmaf(ww, v4.y, a4.y);                    \
    a4.z = fmaf(ww, v4.z, a4.z); a4.w = fmaf(ww, v4.w, a4.w);                    \
  }                                                                              \
  _Pragma("unroll")                                                              \
  for (int off = 16; off <= 32; off <<= 1) {                                     \
    a0.x += __shfl_xor(a0.x, off); a0.y += __shfl_xor(a0.y, off);                \
    a0.z += __shfl_xor(a0.z, off); a0.w += __shfl_xor(a0.w, off);                \
    a1.x += __shfl_xor(a1.x, off); a1.y += __shfl_xor(a1.y, off);                \
    a1.z += __shfl_xor(a1.z, off); a1.w += __shfl_xor(a1.w, off);                \
    a2.x += __shfl_xor(a2.x, off); a2.y += __shfl_xor(a2.y, off);                \
    a2.z += __shfl_xor(a2.z, off); a2.w += __shfl_xor(a2.w, off);                \
    a3.x += __shfl_xor(a3.x, off); a3.y += __shfl_xor(a3.y, off);                \
    a3.z += __shfl_xor(a3.z, off); a3.w += __shfl_xor(a3.w, off);                \
    a4.x += __shfl_xor(a4.x, off); a4.y += __shfl_xor(a4.y, off);                \
    a4.z += __shfl_xor(a4.z, off); a4.w += __shfl_xor(a4.w, off);                \
  }                                                                              \
  float4 osel = (g == 0) ? a0 : (g == 1) ? a1 : (g == 2) ? a2 : a3;

// Y[r,:] = sum_{j in N(r)} X[j,:]
__global__ __launch_bounds__(256) void spmm_k(const int* __restrict__ adj, const int* __restrict__ deg,
                                              const float* __restrict__ X, float* __restrict__ Y, int n) {
  __shared__ int ljs[4][CAP];
  __shared__ float lws[4][CAP];
  int wv = threadIdx.x >> 6, lane = threadIdx.x & 63;
  int w = blockIdx.x * 4 + wv;
  if (w >= n) return;
  int* lj = ljs[wv]; float* lw = lws[wv];
  int d = deg[w];
  const int* row = adj + (size_t)w * CAP;
  for (int t0 = 0; t0 < d; t0 += 64) {
    int tt = t0 + lane;
    lj[tt] = (tt < d) ? row[tt] : 0;
    lw[tt] = (tt < d) ? 1.0f : 0.0f;
  }
  GATHER_CORE(X)
  float* yr = Y + (size_t)w * FD;
  *(float4*)(yr + g * 64 + (sub << 2)) = osel;
  if (g == 0) *(float4*)(yr + 256 + (sub << 2)) = a4;
}

// gather-scaled spmm: Y[r,:] = sum_{j in N(r)} vals[j] * Xsrc[idxmap[j], :]
__global__ __launch_bounds__(256) void spmm_gs_k(const int* __restrict__ adj, const int* __restrict__ deg,
                                                 const int* __restrict__ idxmap, const float* __restrict__ vals,
                                                 const float* __restrict__ Xsrc, float* __restrict__ Y, int n) {
  __shared__ int ljs[4][CAP];
  __shared__ float lws[4][CAP];
  int wv = threadIdx.x >> 6, lane = threadIdx.x & 63;
  int w = blockIdx.x * 4 + wv;
  if (w >= n) return;
  int* lj = ljs[wv]; float* lw = lws[wv];
  int d = deg[w];
  const int* row = adj + (size_t)w * CAP;
  for (int t0 = 0; t0 < d; t0 += 64) {
    int tt = t0 + lane;
    int j = (tt < d) ? row[tt] : -1;
    lj[tt] = (j >= 0) ? idxmap[j] : 0;
    lw[tt] = (j >= 0) ? vals[j] : 0.0f;
  }
  GATHER_CORE(Xsrc)
  float* yr = Y + (size_t)w * FD;
  *(float4*)(yr + g * 64 + (sub << 2)) = osel;
  if (g == 0) *(float4*)(yr + 256 + (sub << 2)) = a4;
}

// fused unpool + A@Xn with COMPACTED staging: only neighbors with inv>=0 enter
// the gather loop (zero-weight terms are exact no-ops; dropping them only
// changes lane-partial association).
__global__ __launch_bounds__(256) void mspmm_k(const int* __restrict__ adj, const int* __restrict__ deg,
                                               const int* __restrict__ inv,
                                               const float* __restrict__ Xp, float* __restrict__ Y, int n) {
  __shared__ int ljs[4][CAP];
  __shared__ float lws[4][CAP];
  int wv = threadIdx.x >> 6, lane = threadIdx.x & 63;
  int w = blockIdx.x * 4 + wv;
  if (w >= n) return;
  int* lj = ljs[wv]; float* lw = lws[wv];
  int d0 = deg[w];
  const int* row = adj + (size_t)w * CAP;
  unsigned long long lm = (1ull << lane) - 1ull;
  int dc = 0;
  for (int t0 = 0; t0 < d0; t0 += 64) {
    int tt = t0 + lane;
    int p = (tt < d0) ? inv[row[tt]] : -1;
    unsigned long long mk = __ballot(p >= 0);
    if (p >= 0) {
      int pos = dc + __popcll(mk & lm);
      lj[pos] = p;
      lw[pos] = 1.0f;
    }
    dc += (int)__popcll(mk);
  }
  if (lane < 4) { lj[dc + lane] = 0; lw[dc + lane] = 0.0f; }  // pad for t+g overhang
  int d = dc;
  GATHER_CORE(Xp)
  float* yr = Y + (size_t)w * FD;
  *(float4*)(yr + g * 64 + (sub << 2)) = osel;
  if (g == 0) *(float4*)(yr + 256 + (sub << 2)) = a4;
}

// fused masked-softmax GAT row: out = elu( softmax_edges(LR(es_i+ed_j)) @ h )
__global__ __launch_bounds__(256) void gat_k(const int* __restrict__ adj, const int* __restrict__ deg,
                                             const float* __restrict__ h, const float* __restrict__ es,
                                             const float* __restrict__ ed, float* __restrict__ out, int n) {
  __shared__ int ljs[4][CAP];
  __shared__ float lws[4][CAP];
  int wv = threadIdx.x >> 6, lane = threadIdx.x & 63;
  int w = blockIdx.x * 4 + wv;
  if (w >= n) return;
  int* lj = ljs[wv]; float* lw = lws[wv];
  int d = deg[w];
  const int* row = adj + (size_t)w * CAP;
  float esr = es[w];
  float m = -INFINITY;
  for (int t0 = 0; t0 < d; t0 += 64) {
    int tt = t0 + lane;
    int j = (tt < d) ? row[tt] : 0;
    float e = -INFINITY;
    if (tt < d) {
      e = esr + ed[j];
      e = e >= 0.f ? e : 0.2f * e;
    }
    lj[tt] = j;
    lw[tt] = e;
    m = fmaxf(m, e);
  }
  #pragma unroll
  for (int off = 32; off; off >>= 1) m = fmaxf(m, __shfl_xor(m, off));
  float zacc = 0.f;
  for (int t0 = 0; t0 < d; t0 += 64) {
    int tt = t0 + lane;
    float wgt = expf(lw[tt] - m);
    lw[tt] = wgt;
    zacc += wgt;
  }
  #pragma unroll
  for (int off = 32; off; off >>= 1) zacc += __shfl_xor(zacc, off);
  GATHER_CORE(h)
  float* yr = out + (size_t)w * FD;
  float4 o;
  o.x = osel.x / zacc; o.y = osel.y / zacc; o.z = osel.z / zacc; o.w = osel.w / zacc;
  o.x = o.x > 0.f ? o.x : expm1f(o.x);
  o.y = o.y > 0.f ? o.y : expm1f(o.y);
  o.z = o.z > 0.f ? o.z : expm1f(o.z);
  o.w = o.w > 0.f ? o.w : expm1f(o.w);
  *(float4*)(yr + g * 64 + (sub << 2)) = o;
  if (g == 0) {
    float4 o4;
    o4.x = a4.x / zacc; o4.y = a4.y / zacc; o4.z = a4.z / zacc; o4.w = a4.w / zacc;
    o4.x = o4.x > 0.f ? o4.x : expm1f(o4.x);
    o4.y = o4.y > 0.f ? o4.y : expm1f(o4.y);
    o4.z = o4.z > 0.f ? o4.z : expm1f(o4.z);
    o4.w = o4.w > 0.f ? o4.w : expm1f(o4.w);
    *(float4*)(yr + 256 + (sub << 2)) = o4;
  }
}

// ---------------- fp32 tiled GEMM: C[n x 320] = A[n x K] @ W[K x 320] (+bias)(+add) ----------------
// Optional: A2 column-concat (k >= ksplit reads A2); rowidx/rowscale row-gather
// (A row = rowidx[r], scaled by rowscale[r] — fuses pool-gather into the GEMM).
__global__ __launch_bounds__(256) void gemm_k(const float* __restrict__ A, const float* __restrict__ A2,
                                              int ksplit,
                                              const int* __restrict__ rowidx, const float* __restrict__ rowscale,
                                              const float* __restrict__ W,
                                              const float* __restrict__ bias, const float* __restrict__ add,
                                              float* __restrict__ C, int n, int K) {
  __shared__ float As[16][68];
  __shared__ float Bs[16][68];
  int t = threadIdx.x;
  int tx = t & 15, ty = t >> 4;
  int row0 = blockIdx.x * 64, col0 = blockIdx.y * 64;
  float acc[4][4] = {};
  int ar = t >> 2;
  int ak = (t & 3) << 2;
  int bk = t >> 4;
  int bc = (t & 15) << 2;
  int grow = row0 + ar;
  int srow = grow;
  float sscale = 1.0f;
  if (grow < n && rowidx) { srow = rowidx[grow]; sscale = rowscale[grow]; }
  for (int k0 = 0; k0 < K; k0 += 16) {
    float4 av = make_float4(0.f, 0.f, 0.f, 0.f);
    int kk = k0 + ak;
    if (grow < n) {
      const float* src;
      if (A2 && kk >= ksplit) src = A2 + (size_t)srow * (K - ksplit) + (kk - ksplit);
      else                    src = A  + (size_t)srow * (A2 ? ksplit : K) + kk;
      av = *(const float4*)src;
      if (rowidx) { av.x *= sscale; av.y *= sscale; av.z *= sscale; av.w *= sscale; }
    }
    As[ak + 0][ar] = av.x; As[ak + 1][ar] = av.y; As[ak + 2][ar] = av.z; As[ak + 3][ar] = av.w;
    float4 bv = *(const float4*)(W + (size_t)(k0 + bk) * FD + col0 + bc);
    *(float4*)&Bs[bk][bc] = bv;
    __syncthreads();
#pragma unroll
    for (int kkk = 0; kkk < 16; ++kkk) {
      float af[4], bf[4];
      *(float4*)af = *(const float4*)&As[kkk][ty << 2];
      *(float4*)bf = *(const float4*)&Bs[kkk][tx << 2];
#pragma unroll
      for (int i = 0; i < 4; ++i)
#pragma unroll
        for (int j = 0; j < 4; ++j) acc[i][j] = fmaf(af[i], bf[j], acc[i][j]);
    }
    __syncthreads();
  }
#pragma unroll
  for (int i = 0; i < 4; ++i) {
    int r = row0 + (ty << 2) + i;
    if (r >= n) continue;
    int c = col0 + (tx << 2);
    float4 v;
    v.x = acc[i][0]; v.y = acc[i][1]; v.z = acc[i][2]; v.w = acc[i][3];
    if (bias) { v.x += bias[c]; v.y += bias[c + 1]; v.z += bias[c + 2]; v.w += bias[c + 3]; }
    if (add) {
      const float* ad = add + (size_t)r * FD + c;
      v.x += ad[0]; v.y += ad[1]; v.z += ad[2]; v.w += ad[3];
    }
    *(float4*)(C + (size_t)r * FD + c) = v;
  }
}

static inline unsigned cdiv(int a, int b) { return (unsigned)((a + b - 1) / b); }

static void launch_gemm(const float* A, const float* W, const float* bias, const float* add,
                        float* C, int n, int K, hipStream_t stream, const float* A2 = nullptr,
                        int ksplit = 0, const int* rowidx = nullptr, const float* rowscale = nullptr) {
  gemm_k<<<dim3(cdiv(n, 64), 5), dim3(256), 0, stream>>>(A, A2, ksplit, rowidx, rowscale,
                                                         W, bias, add, C, n, K);
}

// ---------------- GAT helpers ----------------
__global__ __launch_bounds__(256) void esed_k(const float* __restrict__ h, const float* __restrict__ a,
                                              float* __restrict__ es, float* __restrict__ ed, int n) {
  int w = blockIdx.x * 4 + (threadIdx.x >> 6);
  int lane = threadIdx.x & 63;
  if (w >= n) return;
  const float* hr = h + (size_t)w * FD;
  const float* a2 = a + FD;
  float sa = 0.f, sb = 0.f;
#pragma unroll
  for (int c = 0; c < 5; ++c) {
    float hv = hr[lane + 64 * c];
    sa += hv * a[lane + 64 * c];
    sb += hv * a2[lane + 64 * c];
  }
  for (int o = 32; o; o >>= 1) { sa += __shfl_xor(sa, o); sb += __shfl_xor(sb, o); }
  if (lane == 0) { es[w] = sa; ed[w] = sb; }
}

// ---------------- pooling: fused score + key build + rank zero ----------------
__global__ __launch_bounds__(256) void scorekey_k(const float* __restrict__ X, const float* __restrict__ pw,
                                                  const float* __restrict__ pb,
                                                  unsigned long long* __restrict__ keys,
                                                  int* __restrict__ rank, int n) {
  int w = blockIdx.x * 4 + (threadIdx.x >> 6);
  int lane = threadIdx.x & 63;
  if (w >= n) return;
  const float* xr = X + (size_t)w * FD;
  float s = 0.f;
#pragma unroll
  for (int c = 0; c < 5; ++c) s += xr[lane + 64 * c] * pw[lane + 64 * c];
  for (int o = 32; o; o >>= 1) s += __shfl_xor(s, o);
  if (lane == 0) {
    float u = (s + pb[0]) / 100.0f;
    float sc = 1.0f / (1.0f + expf(-u));
    keys[w] = ((unsigned long long)__float_as_uint(sc) << 32) | (unsigned int)(~w);
    rank[w] = 0;
  }
}

#define RANK_TILE 1024
__global__ __launch_bounds__(256) void rank_count_k(const unsigned long long* __restrict__ keys,
                                                    int n, int jchunk, int* __restrict__ rank) {
  __shared__ unsigned long long tile[RANK_TILE];
  int i = blockIdx.x * 256 + threadIdx.x;
  unsigned long long my = (i < n) ? keys[i] : 0ull;
  int j0 = blockIdx.y * jchunk;
  int jend = j0 + jchunk; if (jend > n) jend = n;
  int cnt = 0;
  for (int t0 = j0; t0 < jend; t0 += RANK_TILE) {
    int m = jend - t0; if (m > RANK_TILE) m = RANK_TILE;
    for (int t = threadIdx.x; t < m; t += 256) tile[t] = keys[t0 + t];
    __syncthreads();
    for (int t = 0; t < m; ++t) cnt += (tile[t] > my) ? 1 : 0;
    __syncthreads();
  }
  if (i < n && cnt) atomicAdd(&rank[i], cnt);
}

__global__ __launch_bounds__(256) void rank_scatter_k(const unsigned long long* __restrict__ keys,
                                                      const int* __restrict__ rank, int n, int k,
                                                      int* __restrict__ idx_out, float* __restrict__ vals_out,
                                                      int* __restrict__ inv) {
  int i = blockIdx.x * 256 + threadIdx.x;
  if (i >= n) return;
  int r = rank[i];
  inv[i] = (r < k) ? r : -1;
  if (r < k) {
    idx_out[r] = i;
    vals_out[r] = __uint_as_float((unsigned int)(keys[i] >> 32));
  }
}

// ---------------- host ----------------
static inline dim3 wgrid(int n) { return dim3((unsigned)((n + 3) / 4)); }

struct TopkBufs { unsigned long long* keys; int* rank; };

static void launch_topk(int n, int k, int* idx_out, float* vals_out, int* inv,
                        TopkBufs tb, hipStream_t stream) {
  const int JS = 8;
  int jchunk = (n + JS - 1) / JS;
  rank_count_k<<<dim3(cdiv(n, 256), JS), dim3(256), 0, stream>>>(tb.keys, n, jchunk, tb.rank);
  rank_scatter_k<<<cdiv(n, 256), dim3(256), 0, stream>>>(tb.keys, tb.rank, n, k, idx_out, vals_out, inv);
}

extern "C" void kernel_launch(void* const* d_in, const int* in_sizes, int n_in,
                              void* d_out, int out_size, void* d_ws, size_t ws_size,
                              hipStream_t stream) {
  const float* A      = (const float*)d_in[0];
  const float* X0     = (const float*)d_in[1];
  const float* sg_W   = (const float*)d_in[2];
  const float* sg_a   = (const float*)d_in[3];
  const float* bg_W   = (const float*)d_in[4];
  const float* bg_a   = (const float*)d_in[5];
  const float* eg_W   = (const float*)d_in[6];
  const float* eg_a   = (const float*)d_in[7];
  const float* down_W = (const float*)d_in[8];
  const float* down_b = (const float*)d_in[9];
  const float* up_W   = (const float*)d_in[10];
  const float* up_b   = (const float*)d_in[11];
  const float* pool_w = (const float*)d_in[12];
  const float* pool_b = (const float*)d_in[13];
  float* out = (float*)d_out;
  char* ws = (char*)d_ws;

  size_t off = 0;
  auto alloc = [&](size_t bytes) -> char* {
    char* p = ws + off;
    off += (bytes + 255) & ~(size_t)255;
    return p;
  };
  int* adj0  = (int*)alloc((size_t)N0 * CAP * 4);
  int* deg0  = (int*)alloc((size_t)N0 * 4);
  int* adj1a = (int*)alloc((size_t)NN1 * CAP * 4);
  int* deg1a = (int*)alloc((size_t)NN1 * 4);
  int* adj1b = (int*)alloc((size_t)NN1 * CAP * 4);
  int* deg1b = (int*)alloc((size_t)NN1 * 4);
  int* adj2  = (int*)alloc((size_t)NN2 * CAP * 4);
  int* deg2  = (int*)alloc((size_t)NN2 * 4);
  int* inv0a = (int*)alloc((size_t)N0 * 4);
  int* inv0b = (int*)alloc((size_t)N0 * 4);
  int* inv1a = (int*)alloc((size_t)NN1 * 4);
  int* inv1b = (int*)alloc((size_t)NN1 * 4);
  int* idx0a = (int*)alloc((size_t)NN1 * 4);
  int* idx0b = (int*)alloc((size_t)NN1 * 4);
  int* idx1a = (int*)alloc((size_t)NN2 * 4);
  int* idx1b = (int*)alloc((size_t)NN2 * 4);
  unsigned long long* keys = (unsigned long long*)alloc((size_t)N0 * 8);
  int* rankb = (int*)alloc((size_t)N0 * 4);
  float* vals   = (float*)alloc((size_t)N0 * 4);
  float* es     = (float*)alloc((size_t)N0 * 4);
  float* ed     = (float*)alloc((size_t)N0 * 4);
  float* hbuf   = (float*)alloc((size_t)N0 * FD * 4);
  float* S      = (float*)alloc((size_t)N0 * FD * 4);
  float* Xcur   = (float*)alloc((size_t)N0 * FD * 4);
  float* d0a    = (float*)alloc((size_t)N0 * FD * 4);
  float* d1a    = (float*)alloc((size_t)NN1 * FD * 4);
  float* d0b    = (float*)alloc((size_t)N0 * FD * 4);
  float* d1b    = (float*)alloc((size_t)NN1 * FD * 4);
  float* Xb     = (float*)alloc((size_t)NN2 * FD * 4);
  float* Xu1    = (float*)alloc((size_t)NN1 * FD * 4);
  float* Xu0    = (float*)alloc((size_t)N0 * FD * 4);

  TopkBufs tb{keys, rankb};
  dim3 b256(256);

  build_adj_k<<<wgrid(N0), b256, 0, stream>>>(A, adj0, deg0);

  float* orgX = out + (size_t)N0 * FD;   // "start" output, also org_X
  launch_gemm(X0, sg_W, nullptr, nullptr, hbuf, N0, FD, stream);
  esed_k<<<wgrid(N0), b256, 0, stream>>>(hbuf, sg_a, es, ed, N0);
  gat_k<<<wgrid(N0), b256, 0, stream>>>(adj0, deg0, hbuf, es, ed, orgX, N0);

  const float* Xin = orgX;
  for (int pass = 0; pass < 2; ++pass) {
    int* idx0p = pass ? idx0b : idx0a;
    int* inv0p = pass ? inv0b : inv0a;
    int* idx1p = pass ? idx1b : idx1a;
    int* inv1p = pass ? inv1b : inv1a;
    int* adj1p = pass ? adj1b : adj1a;
    int* deg1p = pass ? deg1b : deg1a;
    float* d0p = pass ? d0b : d0a;
    float* d1p = pass ? d1b : d1a;

    // ---- down level 0 (n = N0) ----
    spmm_k<<<wgrid(N0), b256, 0, stream>>>(adj0, deg0, Xin, S, N0);
    launch_gemm(S, down_W, down_b, nullptr, d0p, N0, FD, stream);
    scorekey_k<<<wgrid(N0), b256, 0, stream>>>(d0p, pool_w, pool_b, keys, rankb, N0);
    launch_topk(N0, NN1, idx0p, vals, inv0p, tb, stream);
    sub_adj_k<<<wgrid(NN1), b256, 0, stream>>>(adj0, deg0, idx0p, inv0p, adj1p, deg1p, NN1);

    // ---- down level 1 (n = NN1): pool-gather fused into the spmm ----
    spmm_gs_k<<<wgrid(NN1), b256, 0, stream>>>(adj1p, deg1p, idx0p, vals, d0p, S, NN1);
    launch_gemm(S, down_W + FD * FD, down_b + FD, nullptr, d1p, NN1, FD, stream);
    scorekey_k<<<wgrid(NN1), b256, 0, stream>>>(d1p, pool_w + FD, pool_b + 1, keys, rankb, NN1);
    launch_topk(NN1, NN2, idx1p, vals, inv1p, tb, stream);
    sub_adj_k<<<wgrid(NN2), b256, 0, stream>>>(adj1p, deg1p, idx1p, inv1p, adj2, deg2, NN2);

    // ---- bottom GAT (n = NN2): pool-gather fused into the GEMM A-loader ----
    launch_gemm(d1p, bg_W, nullptr, nullptr, hbuf, NN2, FD, stream, nullptr, 0, idx1p, vals);
    esed_k<<<wgrid(NN2), b256, 0, stream>>>(hbuf, bg_a, es, ed, NN2);
    gat_k<<<wgrid(NN2), b256, 0, stream>>>(adj2, deg2, hbuf, es, ed, Xb, NN2);

    // ---- up path: ALWAYS pass-1 ("a") graph state, per reference indexing ----
    mspmm_k<<<wgrid(NN1), b256, 0, stream>>>(adj1a, deg1a, inv1a, Xb, S, NN1);
    launch_gemm(S, up_W, up_b, d1a, Xu1, NN1, FD, stream);
    mspmm_k<<<wgrid(N0), b256, 0, stream>>>(adj0, deg0, inv0a, Xu1, S, N0);
    launch_gemm(S, up_W + FD * FD, up_b + FD, d0a, Xu0, N0, FD, stream);

    // ---- end GAT on concat([Xu0, org_X]) fused into the GEMM A-loader ----
    launch_gemm(Xu0, eg_W, nullptr, nullptr, hbuf, N0, 2 * FD, stream, orgX, FD);
    esed_k<<<wgrid(N0), b256, 0, stream>>>(hbuf, eg_a, es, ed, N0);
    float* egout = pass ? out : Xcur;
    gat_k<<<wgrid(N0), b256, 0, stream>>>(adj0, deg0, hbuf, es, ed, egout, N0);
    Xin = egout;
  }
}

// Round 7
// 1393.505 us; speedup vs baseline: 1.1533x; 1.0546x over previous
//
#include <hip/hip_runtime.h>
#include <cstdint>
#include <cmath>

#define N0   6144
#define FD   320
#define NN1  4915
#define NN2  2949
#define CAP  384

// ---------------- adjacency build: dense row -> compact column list ----------------
__global__ __launch_bounds__(256) void build_adj_k(const float* __restrict__ A,
                                                   int* __restrict__ adj, int* __restrict__ deg) {
  int w = blockIdx.x * 4 + (threadIdx.x >> 6);
  int lane = threadIdx.x & 63;
  if (w >= N0) return;
  const float* row = A + (size_t)w * N0;
  int* dst = adj + (size_t)w * CAP;
  int base = 0;
  unsigned long long lm = (1ull << lane) - 1ull;
  for (int j0 = 0; j0 < N0; j0 += 256) {
    float4 v = *(const float4*)(row + j0 + (lane << 2));
    bool f0 = v.x > 0.f, f1 = v.y > 0.f, f2 = v.z > 0.f, f3 = v.w > 0.f;
    unsigned long long m0 = __ballot(f0), m1 = __ballot(f1), m2 = __ballot(f2), m3 = __ballot(f3);
    int p = base + __popcll(m0 & lm) + __popcll(m1 & lm) + __popcll(m2 & lm) + __popcll(m3 & lm);
    int c0 = j0 + (lane << 2);
    if (f0) dst[p++] = c0;
    if (f1) dst[p++] = c0 + 1;
    if (f2) dst[p++] = c0 + 2;
    if (f3) dst[p++] = c0 + 3;
    base += __popcll(m0) + __popcll(m1) + __popcll(m2) + __popcll(m3);
  }
  if (lane == 0) deg[w] = base;
}

// subgraph adjacency: new row r <- old row idx[r], keep cols with inv[c]>=0, renumber
__global__ __launch_bounds__(256) void sub_adj_k(const int* __restrict__ adjs, const int* __restrict__ degs,
                                                 const int* __restrict__ idx, const int* __restrict__ inv,
                                                 int* __restrict__ adjd, int* __restrict__ degd, int k) {
  int w = blockIdx.x * 4 + (threadIdx.x >> 6);
  int lane = threadIdx.x & 63;
  if (w >= k) return;
  int o = idx[w];
  int d = degs[o];
  const int* src = adjs + (size_t)o * CAP;
  int* dst = adjd + (size_t)w * CAP;
  int base = 0;
  for (int t0 = 0; t0 < d; t0 += 64) {
    int tt = t0 + lane;
    int p = -1;
    if (tt < d) p = inv[src[tt]];
    unsigned long long m = __ballot(p >= 0);
    if (p >= 0) dst[base + __popcll(m & ((1ull << lane) - 1ull))] = p;
    base += (int)__popcll(m);
  }
  if (lane == 0) degd[w] = base;
}

// ================= tiled gather family =================
// One wave per row. (index, weight) staged in LDS; 4 neighbors in flight
// (group g = lane>>4), sub = lane&15 covers cols sub*4 + 64*c (c=0..4) as float4;
// xor-reduce over groups {16,32}; group g stores chunk g, group 0 also chunk 4.
#define GATHER_CORE(XSRC)                                                        \
  int sub = lane & 15, g = lane >> 4;                                            \
  float4 a0 = {0,0,0,0}, a1 = {0,0,0,0}, a2 = {0,0,0,0}, a3 = {0,0,0,0}, a4 = {0,0,0,0}; \
  _Pragma("unroll 2")                                                            \
  for (int t = 0; t < d; t += 4) {                                               \
    int jj = lj[t + g];                                                          \
    float ww = lw[t + g];                                                        \
    const float* base = XSRC + (size_t)jj * FD + (sub << 2);                     \
    float4 v0 = *(const float4*)(base);                                          \
    float4 v1 = *(const float4*)(base + 64);                                     \
    float4 v2 = *(const float4*)(base + 128);                                    \
    float4 v3 = *(const float4*)(base + 192);                                    \
    float4 v4 = *(const float4*)(base + 256);                                    \
    a0.x = fmaf(ww, v0.x, a0.x); a0.y = fmaf(ww, v0.y, a0.y);                    \
    a0.z = fmaf(ww, v0.z, a0.z); a0.w = fmaf(ww, v0.w, a0.w);                    \
    a1.x = fmaf(ww, v1.x, a1.x); a1.y = fmaf(ww, v1.y, a1.y);                    \
    a1.z = fmaf(ww, v1.z, a1.z); a1.w = fmaf(ww, v1.w, a1.w);                    \
    a2.x = fmaf(ww, v2.x, a2.x); a2.y = fmaf(ww, v2.y, a2.y);                    \
    a2.z = fmaf(ww, v2.z, a2.z); a2.w = fmaf(ww, v2.w, a2.w);                    \
    a3.x = fmaf(ww, v3.x, a3.x); a3.y = fmaf(ww, v3.y, a3.y);                    \
    a3.z = fmaf(ww, v3.z, a3.z); a3.w = fmaf(ww, v3.w, a3.w);                    \
    a4.x = fmaf(ww, v4.x, a4.x); a4.y = fmaf(ww, v4.y, a4.y);                    \
    a4.z = fmaf(ww, v4.z, a4.z); a4.w = fmaf(ww, v4.w, a4.w);                    \
  }                                                                              \
  _Pragma("unroll")                                                              \
  for (int off = 16; off <= 32; off <<= 1) {                                     \
    a0.x += __shfl_xor(a0.x, off); a0.y += __shfl_xor(a0.y, off);                \
    a0.z += __shfl_xor(a0.z, off); a0.w += __shfl_xor(a0.w, off);                \
    a1.x += __shfl_xor(a1.x, off); a1.y += __shfl_xor(a1.y, off);                \
    a1.z += __shfl_xor(a1.z, off); a1.w += __shfl_xor(a1.w, off);                \
    a2.x += __shfl_xor(a2.x, off); a2.y += __shfl_xor(a2.y, off);                \
    a2.z += __shfl_xor(a2.z, off); a2.w += __shfl_xor(a2.w, off);                \
    a3.x += __shfl_xor(a3.x, off); a3.y += __shfl_xor(a3.y, off);                \
    a3.z += __shfl_xor(a3.z, off); a3.w += __shfl_xor(a3.w, off);                \
    a4.x += __shfl_xor(a4.x, off); a4.y += __shfl_xor(a4.y, off);                \
    a4.z += __shfl_xor(a4.z, off); a4.w += __shfl_xor(a4.w, off);                \
  }                                                                              \
  float4 osel = (g == 0) ? a0 : (g == 1) ? a1 : (g == 2) ? a2 : a3;

// Y[r,:] = sum_{j in N(r)} X[j,:]
__global__ __launch_bounds__(256) void spmm_k(const int* __restrict__ adj, const int* __restrict__ deg,
                                              const float* __restrict__ X, float* __restrict__ Y, int n) {
  __shared__ int ljs[4][CAP];
  __shared__ float lws[4][CAP];
  int wv = threadIdx.x >> 6, lane = threadIdx.x & 63;
  int w = blockIdx.x * 4 + wv;
  if (w >= n) return;
  int* lj = ljs[wv]; float* lw = lws[wv];
  int d = deg[w];
  const int* row = adj + (size_t)w * CAP;
  for (int t0 = 0; t0 < d; t0 += 64) {
    int tt = t0 + lane;
    lj[tt] = (tt < d) ? row[tt] : 0;
    lw[tt] = (tt < d) ? 1.0f : 0.0f;
  }
  GATHER_CORE(X)
  float* yr = Y + (size_t)w * FD;
  *(float4*)(yr + g * 64 + (sub << 2)) = osel;
  if (g == 0) *(float4*)(yr + 256 + (sub << 2)) = a4;
}

// fused level-1 down: builds subgraph adjacency row (sub_adj) AND does the
// pool-gathered spmm in one kernel. Uses idx[inv[j]] == j to collapse the
// double indirection: staged lj = original j, lw = vals[inv[j]].
// Summation order identical to the old sub_adj+spmm_gs pair (ascending j).
__global__ __launch_bounds__(256) void down1_k(const int* __restrict__ adjs, const int* __restrict__ degs,
                                               const int* __restrict__ idx, const int* __restrict__ inv,
                                               const float* __restrict__ vals,
                                               const float* __restrict__ Xsrc,
                                               int* __restrict__ adjd, int* __restrict__ degd,
                                               float* __restrict__ Y, int n) {
  __shared__ int ljs[4][CAP];
  __shared__ float lws[4][CAP];
  int wv = threadIdx.x >> 6, lane = threadIdx.x & 63;
  int w = blockIdx.x * 4 + wv;
  if (w >= n) return;
  int* lj = ljs[wv]; float* lw = lws[wv];
  int o = idx[w];
  int d0 = degs[o];
  const int* src = adjs + (size_t)o * CAP;
  int* dst = adjd + (size_t)w * CAP;
  unsigned long long lm = (1ull << lane) - 1ull;
  int dc = 0;
  for (int t0 = 0; t0 < d0; t0 += 64) {
    int tt = t0 + lane;
    int j = (tt < d0) ? src[tt] : -1;
    int p = (j >= 0) ? inv[j] : -1;
    unsigned long long mk = __ballot(p >= 0);
    if (p >= 0) {
      int pos = dc + __popcll(mk & lm);
      dst[pos] = p;
      lj[pos] = j;
      lw[pos] = vals[p];
    }
    dc += (int)__popcll(mk);
  }
  if (lane < 4) { lj[dc + lane] = 0; lw[dc + lane] = 0.0f; }  // pad for t+g overhang
  if (lane == 0) degd[w] = dc;
  int d = dc;
  GATHER_CORE(Xsrc)
  float* yr = Y + (size_t)w * FD;
  *(float4*)(yr + g * 64 + (sub << 2)) = osel;
  if (g == 0) *(float4*)(yr + 256 + (sub << 2)) = a4;
}

// fused unpool + A@Xn with COMPACTED staging: only neighbors with inv>=0 enter
// the gather loop.
__global__ __launch_bounds__(256) void mspmm_k(const int* __restrict__ adj, const int* __restrict__ deg,
                                               const int* __restrict__ inv,
                                               const float* __restrict__ Xp, float* __restrict__ Y, int n) {
  __shared__ int ljs[4][CAP];
  __shared__ float lws[4][CAP];
  int wv = threadIdx.x >> 6, lane = threadIdx.x & 63;
  int w = blockIdx.x * 4 + wv;
  if (w >= n) return;
  int* lj = ljs[wv]; float* lw = lws[wv];
  int d0 = deg[w];
  const int* row = adj + (size_t)w * CAP;
  unsigned long long lm = (1ull << lane) - 1ull;
  int dc = 0;
  for (int t0 = 0; t0 < d0; t0 += 64) {
    int tt = t0 + lane;
    int p = (tt < d0) ? inv[row[tt]] : -1;
    unsigned long long mk = __ballot(p >= 0);
    if (p >= 0) {
      int pos = dc + __popcll(mk & lm);
      lj[pos] = p;
      lw[pos] = 1.0f;
    }
    dc += (int)__popcll(mk);
  }
  if (lane < 4) { lj[dc + lane] = 0; lw[dc + lane] = 0.0f; }
  int d = dc;
  GATHER_CORE(Xp)
  float* yr = Y + (size_t)w * FD;
  *(float4*)(yr + g * 64 + (sub << 2)) = osel;
  if (g == 0) *(float4*)(yr + 256 + (sub << 2)) = a4;
}

// fused masked-softmax GAT row: out = elu( softmax_edges(LR(es_i+ed_j)) @ h )
__global__ __launch_bounds__(256) void gat_k(const int* __restrict__ adj, const int* __restrict__ deg,
                                             const float* __restrict__ h, const float* __restrict__ es,
                                             const float* __restrict__ ed, float* __restrict__ out, int n) {
  __shared__ int ljs[4][CAP];
  __shared__ float lws[4][CAP];
  int wv = threadIdx.x >> 6, lane = threadIdx.x & 63;
  int w = blockIdx.x * 4 + wv;
  if (w >= n) return;
  int* lj = ljs[wv]; float* lw = lws[wv];
  int d = deg[w];
  const int* row = adj + (size_t)w * CAP;
  float esr = es[w];
  float m = -INFINITY;
  for (int t0 = 0; t0 < d; t0 += 64) {
    int tt = t0 + lane;
    int j = (tt < d) ? row[tt] : 0;
    float e = -INFINITY;
    if (tt < d) {
      e = esr + ed[j];
      e = e >= 0.f ? e : 0.2f * e;
    }
    lj[tt] = j;
    lw[tt] = e;
    m = fmaxf(m, e);
  }
  #pragma unroll
  for (int off = 32; off; off >>= 1) m = fmaxf(m, __shfl_xor(m, off));
  float zacc = 0.f;
  for (int t0 = 0; t0 < d; t0 += 64) {
    int tt = t0 + lane;
    float wgt = expf(lw[tt] - m);
    lw[tt] = wgt;
    zacc += wgt;
  }
  #pragma unroll
  for (int off = 32; off; off >>= 1) zacc += __shfl_xor(zacc, off);
  GATHER_CORE(h)
  float* yr = out + (size_t)w * FD;
  float4 o;
  o.x = osel.x / zacc; o.y = osel.y / zacc; o.z = osel.z / zacc; o.w = osel.w / zacc;
  o.x = o.x > 0.f ? o.x : expm1f(o.x);
  o.y = o.y > 0.f ? o.y : expm1f(o.y);
  o.z = o.z > 0.f ? o.z : expm1f(o.z);
  o.w = o.w > 0.f ? o.w : expm1f(o.w);
  *(float4*)(yr + g * 64 + (sub << 2)) = o;
  if (g == 0) {
    float4 o4;
    o4.x = a4.x / zacc; o4.y = a4.y / zacc; o4.z = a4.z / zacc; o4.w = a4.w / zacc;
    o4.x = o4.x > 0.f ? o4.x : expm1f(o4.x);
    o4.y = o4.y > 0.f ? o4.y : expm1f(o4.y);
    o4.z = o4.z > 0.f ? o4.z : expm1f(o4.z);
    o4.w = o4.w > 0.f ? o4.w : expm1f(o4.w);
    *(float4*)(yr + 256 + (sub << 2)) = o4;
  }
}

// ---------------- fp32 tiled GEMM with register prefetch ----------------
// C[n x 320] = A[n x K] @ W[K x 320] (+bias)(+add). Optional A2 column-concat
// (k >= ksplit reads A2) and rowidx/rowscale row-gather.
__global__ __launch_bounds__(256) void gemm_k(const float* __restrict__ A, const float* __restrict__ A2,
                                              int ksplit,
                                              const int* __restrict__ rowidx, const float* __restrict__ rowscale,
                                              const float* __restrict__ W,
                                              const float* __restrict__ bias, const float* __restrict__ add,
                                              float* __restrict__ C, int n, int K) {
  __shared__ float As[16][68];
  __shared__ float Bs[16][68];
  int t = threadIdx.x;
  int tx = t & 15, ty = t >> 4;
  int row0 = blockIdx.x * 64, col0 = blockIdx.y * 64;
  float acc[4][4] = {};
  int ar = t >> 2;
  int ak = (t & 3) << 2;
  int bk = t >> 4;
  int bc = (t & 15) << 2;
  int grow = row0 + ar;
  int srow = grow;
  float sscale = 1.0f;
  if (grow < n && rowidx) { srow = rowidx[grow]; sscale = rowscale[grow]; }
  auto load_a = [&](int k0) -> float4 {
    float4 av = make_float4(0.f, 0.f, 0.f, 0.f);
    int kk = k0 + ak;
    if (grow < n) {
      const float* src;
      if (A2 && kk >= ksplit) src = A2 + (size_t)srow * (K - ksplit) + (kk - ksplit);
      else                    src = A  + (size_t)srow * (A2 ? ksplit : K) + kk;
      av = *(const float4*)src;
      if (rowidx) { av.x *= sscale; av.y *= sscale; av.z *= sscale; av.w *= sscale; }
    }
    return av;
  };
  float4 av = load_a(0);
  float4 bv = *(const float4*)(W + (size_t)bk * FD + col0 + bc);
  for (int k0 = 0; k0 < K; k0 += 16) {
    As[ak + 0][ar] = av.x; As[ak + 1][ar] = av.y; As[ak + 2][ar] = av.z; As[ak + 3][ar] = av.w;
    *(float4*)&Bs[bk][bc] = bv;
    __syncthreads();
    if (k0 + 16 < K) {
      av = load_a(k0 + 16);
      bv = *(const float4*)(W + (size_t)(k0 + 16 + bk) * FD + col0 + bc);
    }
#pragma unroll
    for (int kkk = 0; kkk < 16; ++kkk) {
      float af[4], bf[4];
      *(float4*)af = *(const float4*)&As[kkk][ty << 2];
      *(float4*)bf = *(const float4*)&Bs[kkk][tx << 2];
#pragma unroll
      for (int i = 0; i < 4; ++i)
#pragma unroll
        for (int j = 0; j < 4; ++j) acc[i][j] = fmaf(af[i], bf[j], acc[i][j]);
    }
    __syncthreads();
  }
#pragma unroll
  for (int i = 0; i < 4; ++i) {
    int r = row0 + (ty << 2) + i;
    if (r >= n) continue;
    int c = col0 + (tx << 2);
    float4 v;
    v.x = acc[i][0]; v.y = acc[i][1]; v.z = acc[i][2]; v.w = acc[i][3];
    if (bias) { v.x += bias[c]; v.y += bias[c + 1]; v.z += bias[c + 2]; v.w += bias[c + 3]; }
    if (add) {
      const float* ad = add + (size_t)r * FD + c;
      v.x += ad[0]; v.y += ad[1]; v.z += ad[2]; v.w += ad[3];
    }
    *(float4*)(C + (size_t)r * FD + c) = v;
  }
}

static inline unsigned cdiv(int a, int b) { return (unsigned)((a + b - 1) / b); }

static void launch_gemm(const float* A, const float* W, const float* bias, const float* add,
                        float* C, int n, int K, hipStream_t stream, const float* A2 = nullptr,
                        int ksplit = 0, const int* rowidx = nullptr, const float* rowscale = nullptr) {
  gemm_k<<<dim3(cdiv(n, 64), 5), dim3(256), 0, stream>>>(A, A2, ksplit, rowidx, rowscale,
                                                         W, bias, add, C, n, K);
}

// ---------------- GAT helpers ----------------
__global__ __launch_bounds__(256) void esed_k(const float* __restrict__ h, const float* __restrict__ a,
                                              float* __restrict__ es, float* __restrict__ ed, int n) {
  int w = blockIdx.x * 4 + (threadIdx.x >> 6);
  int lane = threadIdx.x & 63;
  if (w >= n) return;
  const float* hr = h + (size_t)w * FD;
  const float* a2 = a + FD;
  float sa = 0.f, sb = 0.f;
#pragma unroll
  for (int c = 0; c < 5; ++c) {
    float hv = hr[lane + 64 * c];
    sa += hv * a[lane + 64 * c];
    sb += hv * a2[lane + 64 * c];
  }
  for (int o = 32; o; o >>= 1) { sa += __shfl_xor(sa, o); sb += __shfl_xor(sb, o); }
  if (lane == 0) { es[w] = sa; ed[w] = sb; }
}

// ---------------- pooling: fused score + key build + rank zero ----------------
__global__ __launch_bounds__(256) void scorekey_k(const float* __restrict__ X, const float* __restrict__ pw,
                                                  const float* __restrict__ pb,
                                                  unsigned long long* __restrict__ keys,
                                                  int* __restrict__ rank, int n) {
  int w = blockIdx.x * 4 + (threadIdx.x >> 6);
  int lane = threadIdx.x & 63;
  if (w >= n) return;
  const float* xr = X + (size_t)w * FD;
  float s = 0.f;
#pragma unroll
  for (int c = 0; c < 5; ++c) s += xr[lane + 64 * c] * pw[lane + 64 * c];
  for (int o = 32; o; o >>= 1) s += __shfl_xor(s, o);
  if (lane == 0) {
    float u = (s + pb[0]) / 100.0f;
    float sc = 1.0f / (1.0f + expf(-u));
    keys[w] = ((unsigned long long)__float_as_uint(sc) << 32) | (unsigned int)(~w);
    rank[w] = 0;
  }
}

#define RANK_TILE 1024
__global__ __launch_bounds__(256) void rank_count_k(const unsigned long long* __restrict__ keys,
                                                    int n, int jchunk, int* __restrict__ rank) {
  __shared__ unsigned long long tile[RANK_TILE];
  int i = blockIdx.x * 256 + threadIdx.x;
  unsigned long long my = (i < n) ? keys[i] : 0ull;
  int j0 = blockIdx.y * jchunk;
  int jend = j0 + jchunk; if (jend > n) jend = n;
  int cnt = 0;
  for (int t0 = j0; t0 < jend; t0 += RANK_TILE) {
    int m = jend - t0; if (m > RANK_TILE) m = RANK_TILE;
    for (int t = threadIdx.x; t < m; t += 256) tile[t] = keys[t0 + t];
    __syncthreads();
    for (int t = 0; t < m; ++t) cnt += (tile[t] > my) ? 1 : 0;
    __syncthreads();
  }
  if (i < n && cnt) atomicAdd(&rank[i], cnt);
}

__global__ __launch_bounds__(256) void rank_scatter_k(const unsigned long long* __restrict__ keys,
                                                      const int* __restrict__ rank, int n, int k,
                                                      int* __restrict__ idx_out, float* __restrict__ vals_out,
                                                      int* __restrict__ inv) {
  int i = blockIdx.x * 256 + threadIdx.x;
  if (i >= n) return;
  int r = rank[i];
  inv[i] = (r < k) ? r : -1;
  if (r < k) {
    idx_out[r] = i;
    vals_out[r] = __uint_as_float((unsigned int)(keys[i] >> 32));
  }
}

// ---------------- host ----------------
static inline dim3 wgrid(int n) { return dim3((unsigned)((n + 3) / 4)); }

struct TopkBufs { unsigned long long* keys; int* rank; };

static void launch_topk(int n, int k, int* idx_out, float* vals_out, int* inv,
                        TopkBufs tb, hipStream_t stream) {
  const int JS = 8;
  int jchunk = (n + JS - 1) / JS;
  rank_count_k<<<dim3(cdiv(n, 256), JS), dim3(256), 0, stream>>>(tb.keys, n, jchunk, tb.rank);
  rank_scatter_k<<<cdiv(n, 256), dim3(256), 0, stream>>>(tb.keys, tb.rank, n, k, idx_out, vals_out, inv);
}

extern "C" void kernel_launch(void* const* d_in, const int* in_sizes, int n_in,
                              void* d_out, int out_size, void* d_ws, size_t ws_size,
                              hipStream_t stream) {
  const float* A      = (const float*)d_in[0];
  const float* X0     = (const float*)d_in[1];
  const float* sg_W   = (const float*)d_in[2];
  const float* sg_a   = (const float*)d_in[3];
  const float* bg_W   = (const float*)d_in[4];
  const float* bg_a   = (const float*)d_in[5];
  const float* eg_W   = (const float*)d_in[6];
  const float* eg_a   = (const float*)d_in[7];
  const float* down_W = (const float*)d_in[8];
  const float* down_b = (const float*)d_in[9];
  const float* up_W   = (const float*)d_in[10];
  const float* up_b   = (const float*)d_in[11];
  const float* pool_w = (const float*)d_in[12];
  const float* pool_b = (const float*)d_in[13];
  float* out = (float*)d_out;
  char* ws = (char*)d_ws;

  size_t off = 0;
  auto alloc = [&](size_t bytes) -> char* {
    char* p = ws + off;
    off += (bytes + 255) & ~(size_t)255;
    return p;
  };
  int* adj0  = (int*)alloc((size_t)N0 * CAP * 4);
  int* deg0  = (int*)alloc((size_t)N0 * 4);
  int* adj1a = (int*)alloc((size_t)NN1 * CAP * 4);
  int* deg1a = (int*)alloc((size_t)NN1 * 4);
  int* adj1b = (int*)alloc((size_t)NN1 * CAP * 4);
  int* deg1b = (int*)alloc((size_t)NN1 * 4);
  int* adj2  = (int*)alloc((size_t)NN2 * CAP * 4);
  int* deg2  = (int*)alloc((size_t)NN2 * 4);
  int* inv0a = (int*)alloc((size_t)N0 * 4);
  int* inv0b = (int*)alloc((size_t)N0 * 4);
  int* inv1a = (int*)alloc((size_t)NN1 * 4);
  int* inv1b = (int*)alloc((size_t)NN1 * 4);
  int* idx0a = (int*)alloc((size_t)NN1 * 4);
  int* idx0b = (int*)alloc((size_t)NN1 * 4);
  int* idx1a = (int*)alloc((size_t)NN2 * 4);
  int* idx1b = (int*)alloc((size_t)NN2 * 4);
  unsigned long long* keys = (unsigned long long*)alloc((size_t)N0 * 8);
  int* rankb = (int*)alloc((size_t)N0 * 4);
  float* vals   = (float*)alloc((size_t)N0 * 4);
  float* es     = (float*)alloc((size_t)N0 * 4);
  float* ed     = (float*)alloc((size_t)N0 * 4);
  float* hbuf   = (float*)alloc((size_t)N0 * FD * 4);
  float* S      = (float*)alloc((size_t)N0 * FD * 4);
  float* Xcur   = (float*)alloc((size_t)N0 * FD * 4);
  float* d0a    = (float*)alloc((size_t)N0 * FD * 4);
  float* d1a    = (float*)alloc((size_t)NN1 * FD * 4);
  float* d0b    = (float*)alloc((size_t)N0 * FD * 4);
  float* d1b    = (float*)alloc((size_t)NN1 * FD * 4);
  float* Xb     = (float*)alloc((size_t)NN2 * FD * 4);
  float* Xu1    = (float*)alloc((size_t)NN1 * FD * 4);
  float* Xu0    = (float*)alloc((size_t)N0 * FD * 4);

  TopkBufs tb{keys, rankb};
  dim3 b256(256);

  build_adj_k<<<wgrid(N0), b256, 0, stream>>>(A, adj0, deg0);

  float* orgX = out + (size_t)N0 * FD;   // "start" output, also org_X
  launch_gemm(X0, sg_W, nullptr, nullptr, hbuf, N0, FD, stream);
  esed_k<<<wgrid(N0), b256, 0, stream>>>(hbuf, sg_a, es, ed, N0);
  gat_k<<<wgrid(N0), b256, 0, stream>>>(adj0, deg0, hbuf, es, ed, orgX, N0);

  const float* Xin = orgX;
  for (int pass = 0; pass < 2; ++pass) {
    int* idx0p = pass ? idx0b : idx0a;
    int* inv0p = pass ? inv0b : inv0a;
    int* idx1p = pass ? idx1b : idx1a;
    int* inv1p = pass ? inv1b : inv1a;
    int* adj1p = pass ? adj1b : adj1a;
    int* deg1p = pass ? deg1b : deg1a;
    float* d0p = pass ? d0b : d0a;
    float* d1p = pass ? d1b : d1a;

    // ---- down level 0 (n = N0) ----
    spmm_k<<<wgrid(N0), b256, 0, stream>>>(adj0, deg0, Xin, S, N0);
    launch_gemm(S, down_W, down_b, nullptr, d0p, N0, FD, stream);
    scorekey_k<<<wgrid(N0), b256, 0, stream>>>(d0p, pool_w, pool_b, keys, rankb, N0);
    launch_topk(N0, NN1, idx0p, vals, inv0p, tb, stream);

    // ---- down level 1 (n = NN1): sub_adj + pool-gather spmm fused ----
    down1_k<<<wgrid(NN1), b256, 0, stream>>>(adj0, deg0, idx0p, inv0p, vals, d0p,
                                             adj1p, deg1p, S, NN1);
    launch_gemm(S, down_W + FD * FD, down_b + FD, nullptr, d1p, NN1, FD, stream);
    scorekey_k<<<wgrid(NN1), b256, 0, stream>>>(d1p, pool_w + FD, pool_b + 1, keys, rankb, NN1);
    launch_topk(NN1, NN2, idx1p, vals, inv1p, tb, stream);
    sub_adj_k<<<wgrid(NN2), b256, 0, stream>>>(adj1p, deg1p, idx1p, inv1p, adj2, deg2, NN2);

    // ---- bottom GAT (n = NN2): pool-gather fused into the GEMM A-loader ----
    launch_gemm(d1p, bg_W, nullptr, nullptr, hbuf, NN2, FD, stream, nullptr, 0, idx1p, vals);
    esed_k<<<wgrid(NN2), b256, 0, stream>>>(hbuf, bg_a, es, ed, NN2);
    gat_k<<<wgrid(NN2), b256, 0, stream>>>(adj2, deg2, hbuf, es, ed, Xb, NN2);

    // ---- up path: ALWAYS pass-1 ("a") graph state, per reference indexing ----
    mspmm_k<<<wgrid(NN1), b256, 0, stream>>>(adj1a, deg1a, inv1a, Xb, S, NN1);
    launch_gemm(S, up_W, up_b, d1a, Xu1, NN1, FD, stream);
    mspmm_k<<<wgrid(N0), b256, 0, stream>>>(adj0, deg0, inv0a, Xu1, S, N0);
    launch_gemm(S, up_W + FD * FD, up_b + FD, d0a, Xu0, N0, FD, stream);

    // ---- end GAT on concat([Xu0, org_X]) fused into the GEMM A-loader ----
    launch_gemm(Xu0, eg_W, nullptr, nullptr, hbuf, N0, 2 * FD, stream, orgX, FD);
    esed_k<<<wgrid(N0), b256, 0, stream>>>(hbuf, eg_a, es, ed, N0);
    float* egout = pass ? out : Xcur;
    gat_k<<<wgrid(N0), b256, 0, stream>>>(adj0, deg0, hbuf, es, ed, egout, N0);
    Xin = egout;
  }
}